// Round 1
// baseline (729.114 us; speedup 1.0000x reference)
//
#include <hip/hip_runtime.h>
#include <hip/hip_bf16.h>
#include <math.h>

#define NUM_ITEMS 50000
#define NUM_USERS 16384
#define H0 512
#define LAT 256

// ---------------- transpose W_enc [H0][NUM_ITEMS] -> wt [NUM_ITEMS][H0] ----------------
__global__ void transpose_kernel(const float* __restrict__ src, float* __restrict__ dst) {
    __shared__ float tile[32][33];
    int tx = threadIdx.x, ty = threadIdx.y;            // 32 x 8
    int x0 = blockIdx.x * 32, y0 = blockIdx.y * 32;    // x: item dim, y: h dim
    int x = x0 + tx;
    if (x < NUM_ITEMS) {
#pragma unroll
        for (int j = 0; j < 32; j += 8)
            tile[ty + j][tx] = src[(size_t)(y0 + ty + j) * NUM_ITEMS + x];
    }
    __syncthreads();
#pragma unroll
    for (int j = 0; j < 32; j += 8) {
        int it = x0 + ty + j;
        if (it < NUM_ITEMS)
            dst[(size_t)it * H0 + y0 + tx] = tile[tx][ty + j];
    }
}

// ---------------- counting sort of interactions by user ----------------
__global__ void count_kernel(const int* __restrict__ user, int* __restrict__ cnt, int n) {
    int i = blockIdx.x * blockDim.x + threadIdx.x;
    if (i < n) atomicAdd(&cnt[user[i]], 1);
}

// single block, 1024 threads, 16 values each -> exclusive prefix over 16384 counts
__global__ void scan_kernel(const int* __restrict__ cnt, int* __restrict__ offs,
                            int* __restrict__ cursor) {
    __shared__ int ssum[1024];
    int t = threadIdx.x;
    int base = t * 16;
    int local[16];
    int s = 0;
#pragma unroll
    for (int j = 0; j < 16; ++j) { local[j] = s; s += cnt[base + j]; }
    ssum[t] = s;
    __syncthreads();
    for (int off = 1; off < 1024; off <<= 1) {
        int v = (t >= off) ? ssum[t - off] : 0;
        __syncthreads();
        ssum[t] += v;
        __syncthreads();
    }
    int excl = (t == 0) ? 0 : ssum[t - 1];
#pragma unroll
    for (int j = 0; j < 16; ++j) {
        int o = excl + local[j];
        offs[base + j] = o;
        cursor[base + j] = o;
    }
}

__global__ void scatter_kernel(const int* __restrict__ user, const int* __restrict__ item,
                               const float* __restrict__ rating, int* __restrict__ cursor,
                               int* __restrict__ s_item, float* __restrict__ s_rat, int n) {
    int i = blockIdx.x * blockDim.x + threadIdx.x;
    if (i < n) {
        int u = user[i];
        int pos = atomicAdd(&cursor[u], 1);
        s_item[pos] = item[i];
        s_rat[pos] = rating[i];
    }
}

// ---------------- per-user segment sum + bias + tanh -> x [NUM_USERS][H0] ----------------
__global__ void agg_kernel(const float* __restrict__ wt, const int* __restrict__ offs,
                           const int* __restrict__ ends, const int* __restrict__ s_item,
                           const float* __restrict__ s_rat, const float* __restrict__ b_enc,
                           float* __restrict__ x) {
    int u = blockIdx.x;
    int t = threadIdx.x;   // 256 threads, float2 each -> 512 floats
    float2 acc = make_float2(0.f, 0.f);
    int j0 = offs[u], j1 = ends[u];
    for (int j = j0; j < j1; ++j) {
        int it = s_item[j];
        float r = s_rat[j];
        const float2* row = (const float2*)(wt + (size_t)it * H0);
        float2 v = row[t];
        acc.x += v.x * r;
        acc.y += v.y * r;
    }
    float2 b = ((const float2*)b_enc)[t];
    float2 o;
    o.x = tanhf(acc.x + b.x);
    o.y = tanhf(acc.y + b.y);
    ((float2*)(x + (size_t)u * H0))[t] = o;
}

// ---------------- C[m][n] = tanh(bias[n] + sum_k A[m][k]*B[n][k]) ----------------
// A [M][K], B [Nn][K] row-major, K multiple of 16, M,Nn multiples of 64.
__global__ __launch_bounds__(256) void gemm_bias_tanh(const float* __restrict__ A,
                                                      const float* __restrict__ B,
                                                      const float* __restrict__ bias,
                                                      float* __restrict__ C, int Nn, int K) {
    const int BM = 64, BN = 64, BK = 16;
    __shared__ float As[BK][BM + 1];
    __shared__ float Bs[BK][BN + 1];
    int tid = threadIdx.x;
    int tx = tid & 15, ty = tid >> 4;
    int m0 = blockIdx.x * BM, n0 = blockIdx.y * BN;
    int ra = tid >> 2;         // 0..63  tile row
    int ca = (tid & 3) * 4;    // 0,4,8,12
    float acc[4][4] = {};
    for (int k0 = 0; k0 < K; k0 += BK) {
        float4 av = *(const float4*)&A[(size_t)(m0 + ra) * K + k0 + ca];
        float4 bv = *(const float4*)&B[(size_t)(n0 + ra) * K + k0 + ca];
        As[ca + 0][ra] = av.x; As[ca + 1][ra] = av.y; As[ca + 2][ra] = av.z; As[ca + 3][ra] = av.w;
        Bs[ca + 0][ra] = bv.x; Bs[ca + 1][ra] = bv.y; Bs[ca + 2][ra] = bv.z; Bs[ca + 3][ra] = bv.w;
        __syncthreads();
#pragma unroll
        for (int k = 0; k < BK; ++k) {
            float a[4], b[4];
#pragma unroll
            for (int i = 0; i < 4; ++i) { a[i] = As[k][ty * 4 + i]; b[i] = Bs[k][tx * 4 + i]; }
#pragma unroll
            for (int i = 0; i < 4; ++i)
#pragma unroll
                for (int j = 0; j < 4; ++j) acc[i][j] += a[i] * b[j];
        }
        __syncthreads();
    }
#pragma unroll
    for (int i = 0; i < 4; ++i) {
        int m = m0 + ty * 4 + i;
        float4 o;
        o.x = tanhf(acc[i][0] + bias[n0 + tx * 4 + 0]);
        o.y = tanhf(acc[i][1] + bias[n0 + tx * 4 + 1]);
        o.z = tanhf(acc[i][2] + bias[n0 + tx * 4 + 2]);
        o.w = tanhf(acc[i][3] + bias[n0 + tx * 4 + 3]);
        *(float4*)&C[(size_t)m * Nn + n0 + tx * 4] = o;
    }
}

// ---------------- pred[t] = dot(dec[tu], W_dec[ti]) + b_dec[ti]; per-block sq-err partial ----------------
__global__ __launch_bounds__(256) void predict_kernel(const float* __restrict__ dec,
                                                      const float* __restrict__ W_dec,
                                                      const float* __restrict__ b_dec,
                                                      const int* __restrict__ t_user,
                                                      const int* __restrict__ t_item,
                                                      const float* __restrict__ t_rating,
                                                      float* __restrict__ pred,
                                                      float* __restrict__ partials, int NT) {
    __shared__ float wsum[4];
    int gw = (blockIdx.x * blockDim.x + threadIdx.x) >> 6;  // global wave = target idx
    int lane = threadIdx.x & 63;
    int wid = threadIdx.x >> 6;
    float sq = 0.f;
    if (gw < NT) {
        int tu = t_user[gw], ti = t_item[gw];
        const float4* g = (const float4*)(dec + (size_t)tu * H0);
        const float4* w = (const float4*)(W_dec + (size_t)ti * H0);
        float4 a0 = g[lane * 2], b0 = w[lane * 2];
        float4 a1 = g[lane * 2 + 1], b1 = w[lane * 2 + 1];
        float s = a0.x * b0.x + a0.y * b0.y + a0.z * b0.z + a0.w * b0.w
                + a1.x * b1.x + a1.y * b1.y + a1.z * b1.z + a1.w * b1.w;
#pragma unroll
        for (int off = 32; off; off >>= 1) s += __shfl_xor(s, off, 64);
        if (lane == 0) {
            float p = s + b_dec[ti];
            pred[gw] = p;
            float d = p - t_rating[gw];
            sq = d * d;
        }
    }
    if (lane == 0) wsum[wid] = sq;
    __syncthreads();
    if (threadIdx.x == 0) partials[blockIdx.x] = wsum[0] + wsum[1] + wsum[2] + wsum[3];
}

__global__ void loss_reduce(const float* __restrict__ partials, float* __restrict__ out_loss,
                            int nPart, float invNT) {
    __shared__ float s[256];
    int t = threadIdx.x;
    float a = 0.f;
    for (int i = t; i < nPart; i += 256) a += partials[i];
    s[t] = a;
    __syncthreads();
    for (int off = 128; off; off >>= 1) {
        if (t < off) s[t] += s[t + off];
        __syncthreads();
    }
    if (t == 0) out_loss[0] = s[0] * invNT;
}

extern "C" void kernel_launch(void* const* d_in, const int* in_sizes, int n_in,
                              void* d_out, int out_size, void* d_ws, size_t ws_size,
                              hipStream_t stream) {
    const int* user = (const int*)d_in[0];
    const int* item = (const int*)d_in[1];
    const float* rating = (const float*)d_in[2];
    const int* t_user = (const int*)d_in[3];
    const int* t_item = (const int*)d_in[4];
    const float* t_rating = (const float*)d_in[5];
    const float* W_enc = (const float*)d_in[6];
    const float* b_enc = (const float*)d_in[7];
    const float* W1 = (const float*)d_in[8];
    const float* b1 = (const float*)d_in[9];
    const float* W2 = (const float*)d_in[10];
    const float* b2 = (const float*)d_in[11];
    const float* W_dec = (const float*)d_in[12];
    const float* b_dec = (const float*)d_in[13];
    const int N = in_sizes[0];
    const int NT = in_sizes[3];

    char* ws = (char*)d_ws;
    size_t off = 0;
    auto alloc = [&](size_t bytes) {
        void* p = ws + off;
        off = (off + bytes + 255) & ~(size_t)255;
        return p;
    };
    float* wt = (float*)alloc((size_t)NUM_ITEMS * H0 * 4);       // 102.4 MB
    float* x = (float*)alloc((size_t)NUM_USERS * H0 * 4);        // 32 MB
    float* enc = (float*)alloc((size_t)NUM_USERS * LAT * 4);     // 16 MB
    float* dec = (float*)alloc((size_t)NUM_USERS * H0 * 4);      // 32 MB
    int* cnt = (int*)alloc((size_t)NUM_USERS * 4);
    int* offs = (int*)alloc((size_t)NUM_USERS * 4);
    int* cursor = (int*)alloc((size_t)NUM_USERS * 4);
    int* s_item = (int*)alloc((size_t)N * 4);
    float* s_rat = (float*)alloc((size_t)N * 4);
    const int predBlocks = (NT + 3) / 4;                         // 4 waves (targets) / block
    float* partials = (float*)alloc((size_t)predBlocks * 4);

    float* pred = (float*)d_out;
    float* loss = pred + NT;

    hipMemsetAsync(cnt, 0, (size_t)NUM_USERS * 4, stream);
    transpose_kernel<<<dim3((NUM_ITEMS + 31) / 32, H0 / 32), dim3(32, 8), 0, stream>>>(W_enc, wt);
    count_kernel<<<(N + 255) / 256, 256, 0, stream>>>(user, cnt, N);
    scan_kernel<<<1, 1024, 0, stream>>>(cnt, offs, cursor);
    scatter_kernel<<<(N + 255) / 256, 256, 0, stream>>>(user, item, rating, cursor, s_item, s_rat, N);
    agg_kernel<<<NUM_USERS, 256, 0, stream>>>(wt, offs, cursor, s_item, s_rat, b_enc, x);
    gemm_bias_tanh<<<dim3(NUM_USERS / 64, LAT / 64), 256, 0, stream>>>(x, W1, b1, enc, LAT, H0);
    gemm_bias_tanh<<<dim3(NUM_USERS / 64, H0 / 64), 256, 0, stream>>>(enc, W2, b2, dec, H0, LAT);
    predict_kernel<<<predBlocks, 256, 0, stream>>>(dec, W_dec, b_dec, t_user, t_item, t_rating,
                                                   pred, partials, NT);
    loss_reduce<<<1, 256, 0, stream>>>(partials, loss, predBlocks, 1.0f / NT);
}

// Round 2
// 475.880 us; speedup vs baseline: 1.5321x; 1.5321x over previous
//
#include <hip/hip_runtime.h>
#include <hip/hip_bf16.h>
#include <math.h>

#define NUM_ITEMS 50000
#define NUM_USERS 16384
#define H0 512
#define LAT 256

typedef __attribute__((ext_vector_type(8))) short short8;
typedef __attribute__((ext_vector_type(4))) float floatx4;

__device__ __forceinline__ unsigned short f2bf(float f) {
    union { float f; unsigned i; } u; u.f = f;
    unsigned r = u.i + 0x7fff + ((u.i >> 16) & 1);   // RNE
    return (unsigned short)(r >> 16);
}
__device__ __forceinline__ float bfhi(unsigned v) {  // high ushort -> float
    union { unsigned i; float f; } u; u.i = v & 0xffff0000u; return u.f;
}
__device__ __forceinline__ float bflo(unsigned v) {  // low ushort -> float
    union { unsigned i; float f; } u; u.i = v << 16; return u.f;
}

// ---------------- transpose+cast W_enc [H0][NUM_ITEMS] f32 -> wtb [NUM_ITEMS][H0] bf16 ----------------
__global__ void transpose_kernel(const float* __restrict__ src, unsigned short* __restrict__ dst) {
    __shared__ float tile[32][33];
    int tx = threadIdx.x, ty = threadIdx.y;            // 32 x 8
    int x0 = blockIdx.x * 32, y0 = blockIdx.y * 32;    // x: item dim, y: h dim
    int x = x0 + tx;
    if (x < NUM_ITEMS) {
#pragma unroll
        for (int j = 0; j < 32; j += 8)
            tile[ty + j][tx] = src[(size_t)(y0 + ty + j) * NUM_ITEMS + x];
    }
    __syncthreads();
#pragma unroll
    for (int j = 0; j < 32; j += 8) {
        int it = x0 + ty + j;
        if (it < NUM_ITEMS)
            dst[(size_t)it * H0 + y0 + tx] = f2bf(tile[tx][ty + j]);
    }
}

// ---------------- f32 -> bf16 cast for W1 / W2 ----------------
__global__ void f2bf_kernel(const float* __restrict__ src, unsigned short* __restrict__ dst, int n) {
    int i = blockIdx.x * blockDim.x + threadIdx.x;
    if (i < n) dst[i] = f2bf(src[i]);
}

// ---------------- counting sort of interactions by user ----------------
__global__ void count_kernel(const int* __restrict__ user, int* __restrict__ cnt, int n) {
    int i = blockIdx.x * blockDim.x + threadIdx.x;
    if (i < n) atomicAdd(&cnt[user[i]], 1);
}

__global__ void scan_kernel(const int* __restrict__ cnt, int* __restrict__ offs,
                            int* __restrict__ cursor) {
    __shared__ int ssum[1024];
    int t = threadIdx.x;
    int base = t * 16;
    int local[16];
    int s = 0;
#pragma unroll
    for (int j = 0; j < 16; ++j) { local[j] = s; s += cnt[base + j]; }
    ssum[t] = s;
    __syncthreads();
    for (int off = 1; off < 1024; off <<= 1) {
        int v = (t >= off) ? ssum[t - off] : 0;
        __syncthreads();
        ssum[t] += v;
        __syncthreads();
    }
    int excl = (t == 0) ? 0 : ssum[t - 1];
#pragma unroll
    for (int j = 0; j < 16; ++j) {
        int o = excl + local[j];
        offs[base + j] = o;
        cursor[base + j] = o;
    }
}

__global__ void scatter_kernel(const int* __restrict__ user, const int* __restrict__ item,
                               const float* __restrict__ rating, int* __restrict__ cursor,
                               int* __restrict__ s_item, float* __restrict__ s_rat, int n) {
    int i = blockIdx.x * blockDim.x + threadIdx.x;
    if (i < n) {
        int u = user[i];
        int pos = atomicAdd(&cursor[u], 1);
        s_item[pos] = item[i];
        s_rat[pos] = rating[i];
    }
}

// ---------------- per-user segment sum + bias + tanh -> xb [NUM_USERS][H0] bf16 ----------------
// 256 threads = 4 groups of 64 lanes; group g handles items j0+g, j0+g+4, ... (4-way ILP)
// lane covers elements [8*lane, 8*lane+8) of the 512-wide row (uint4 = 8 bf16 per load).
__global__ __launch_bounds__(256) void agg_kernel(const unsigned short* __restrict__ wtb,
                                                  const int* __restrict__ offs,
                                                  const int* __restrict__ ends,
                                                  const int* __restrict__ s_item,
                                                  const float* __restrict__ s_rat,
                                                  const float* __restrict__ b_enc,
                                                  unsigned short* __restrict__ xb) {
    __shared__ float red[3 * 512];
    int u = blockIdx.x;
    int tid = threadIdx.x;
    int g = tid >> 6, lane = tid & 63;
    float acc[8] = {};
    int j0 = offs[u], j1 = ends[u];
    for (int j = j0 + g; j < j1; j += 4) {
        int it = s_item[j];
        float r = s_rat[j];
        uint4 v = ((const uint4*)(wtb + (size_t)it * H0))[lane];
        acc[0] += bflo(v.x) * r; acc[1] += bfhi(v.x) * r;
        acc[2] += bflo(v.y) * r; acc[3] += bfhi(v.y) * r;
        acc[4] += bflo(v.z) * r; acc[5] += bfhi(v.z) * r;
        acc[6] += bflo(v.w) * r; acc[7] += bfhi(v.w) * r;
    }
    if (g) {
        float4* rp = (float4*)red + (size_t)(g - 1) * 128 + lane * 2;
        rp[0] = make_float4(acc[0], acc[1], acc[2], acc[3]);
        rp[1] = make_float4(acc[4], acc[5], acc[6], acc[7]);
    }
    __syncthreads();
    if (g == 0) {
#pragma unroll
        for (int h = 0; h < 3; ++h) {
            const float* rp = red + h * 512 + lane * 8;
#pragma unroll
            for (int e = 0; e < 8; ++e) acc[e] += rp[e];
        }
        float4 b0 = ((const float4*)b_enc)[lane * 2];
        float4 b1 = ((const float4*)b_enc)[lane * 2 + 1];
        unsigned short o[8];
        o[0] = f2bf(tanhf(acc[0] + b0.x)); o[1] = f2bf(tanhf(acc[1] + b0.y));
        o[2] = f2bf(tanhf(acc[2] + b0.z)); o[3] = f2bf(tanhf(acc[3] + b0.w));
        o[4] = f2bf(tanhf(acc[4] + b1.x)); o[5] = f2bf(tanhf(acc[5] + b1.y));
        o[6] = f2bf(tanhf(acc[6] + b1.z)); o[7] = f2bf(tanhf(acc[7] + b1.w));
        uint4 pk;
        pk.x = (unsigned)o[0] | ((unsigned)o[1] << 16);
        pk.y = (unsigned)o[2] | ((unsigned)o[3] << 16);
        pk.z = (unsigned)o[4] | ((unsigned)o[5] << 16);
        pk.w = (unsigned)o[6] | ((unsigned)o[7] << 16);
        ((uint4*)(xb + (size_t)u * H0))[lane] = pk;
    }
}

// ---------------- bf16 MFMA GEMM: C[m][n] = tanh(bias[n] + sum_k A[m][k]*B[n][k]) -> bf16 ----------------
// A [M][K] bf16, B [Nn][K] bf16 (B^T layout). 128x128 tile, 256 threads (4 waves, 2x2),
// each wave 4x4 grid of 16x16x32 MFMAs. Staging via global_load_lds width=16.
__global__ __launch_bounds__(256) void gemm_mfma(const unsigned short* __restrict__ A,
                                                 const unsigned short* __restrict__ B,
                                                 const float* __restrict__ bias,
                                                 unsigned short* __restrict__ C,
                                                 int Nn, int K) {
    __shared__ unsigned short Ash[128 * 32];
    __shared__ unsigned short Bsh[128 * 32];
    int tid = threadIdx.x;
    int wid = tid >> 6, lane = tid & 63;
    int wave_m = wid & 1, wave_n = wid >> 1;
    int quad = lane >> 4, l16 = lane & 15;
    int m0 = blockIdx.x * 128, n0 = blockIdx.y * 128;
    floatx4 acc[4][4] = {};

    int srow = lane >> 2;          // 0..15 within 16-row chunk
    int scol = (lane & 3) * 8;     // bf16 element offset within 32
    for (int k0 = 0; k0 < K; k0 += 32) {
#pragma unroll
        for (int i = 0; i < 2; ++i) {
            int c = wid * 2 + i;   // chunk 0..7, 16 rows each
            int row = c * 16 + srow;
            const unsigned short* ga = A + (size_t)(m0 + row) * K + k0 + scol;
            const unsigned short* gb = B + (size_t)(n0 + row) * K + k0 + scol;
            __builtin_amdgcn_global_load_lds(
                (const __attribute__((address_space(1))) void*)ga,
                (__attribute__((address_space(3))) void*)((__attribute__((address_space(3))) char*)Ash + c * 1024),
                16, 0, 0);
            __builtin_amdgcn_global_load_lds(
                (const __attribute__((address_space(1))) void*)gb,
                (__attribute__((address_space(3))) void*)((__attribute__((address_space(3))) char*)Bsh + c * 1024),
                16, 0, 0);
        }
        __syncthreads();
        short8 af[4], bfr[4];
#pragma unroll
        for (int i = 0; i < 4; ++i) {
            int ml = wave_m * 64 + i * 16 + l16;
            af[i] = ((const short8*)Ash)[ml * 4 + quad];
            int nl = wave_n * 64 + i * 16 + l16;
            bfr[i] = ((const short8*)Bsh)[nl * 4 + quad];
        }
#pragma unroll
        for (int i = 0; i < 4; ++i)
#pragma unroll
            for (int j = 0; j < 4; ++j)
                acc[i][j] = __builtin_amdgcn_mfma_f32_16x16x32_bf16(af[i], bfr[j], acc[i][j], 0, 0, 0);
        __syncthreads();
    }
#pragma unroll
    for (int j = 0; j < 4; ++j) {
        int col = n0 + wave_n * 64 + j * 16 + l16;
        float bv = bias[col];
#pragma unroll
        for (int i = 0; i < 4; ++i) {
            int rowb = m0 + wave_m * 64 + i * 16 + quad * 4;
#pragma unroll
            for (int r = 0; r < 4; ++r)
                C[(size_t)(rowb + r) * Nn + col] = f2bf(tanhf(acc[i][j][r] + bv));
        }
    }
}

// ---------------- pred[t] = dot(dec_b[tu], W_dec[ti]) + b_dec[ti]; 4 targets per wave ----------------
__global__ __launch_bounds__(256) void predict_kernel(const unsigned short* __restrict__ dec_b,
                                                      const float* __restrict__ W_dec,
                                                      const float* __restrict__ b_dec,
                                                      const int* __restrict__ t_user,
                                                      const int* __restrict__ t_item,
                                                      const float* __restrict__ t_rating,
                                                      float* __restrict__ pred,
                                                      float* __restrict__ partials, int NT) {
    __shared__ float wsum[4];
    int wid = threadIdx.x >> 6, lane = threadIdx.x & 63;
    int base = (blockIdx.x * 4 + wid) * 4;
    float sq = 0.f;
    int tu[4], ti[4];
    uint4 gv[4];
    float4 wv0[4], wv1[4];
#pragma unroll
    for (int t = 0; t < 4; ++t) {
        int idx = min(base + t, NT - 1);
        tu[t] = t_user[idx];
        ti[t] = t_item[idx];
    }
#pragma unroll
    for (int t = 0; t < 4; ++t) {
        gv[t] = ((const uint4*)(dec_b + (size_t)tu[t] * H0))[lane];
        const float4* w = (const float4*)(W_dec + (size_t)ti[t] * H0);
        wv0[t] = w[lane * 2];
        wv1[t] = w[lane * 2 + 1];
    }
#pragma unroll
    for (int t = 0; t < 4; ++t) {
        float s = bflo(gv[t].x) * wv0[t].x + bfhi(gv[t].x) * wv0[t].y
                + bflo(gv[t].y) * wv0[t].z + bfhi(gv[t].y) * wv0[t].w
                + bflo(gv[t].z) * wv1[t].x + bfhi(gv[t].z) * wv1[t].y
                + bflo(gv[t].w) * wv1[t].z + bfhi(gv[t].w) * wv1[t].w;
#pragma unroll
        for (int off = 32; off; off >>= 1) s += __shfl_xor(s, off, 64);
        if (lane == 0 && base + t < NT) {
            float p = s + b_dec[ti[t]];
            pred[base + t] = p;
            float d = p - t_rating[base + t];
            sq += d * d;
        }
    }
    if (lane == 0) wsum[wid] = sq;
    __syncthreads();
    if (threadIdx.x == 0) partials[blockIdx.x] = wsum[0] + wsum[1] + wsum[2] + wsum[3];
}

__global__ void loss_reduce(const float* __restrict__ partials, float* __restrict__ out_loss,
                            int nPart, float invNT) {
    __shared__ float s[256];
    int t = threadIdx.x;
    float a = 0.f;
    for (int i = t; i < nPart; i += 256) a += partials[i];
    s[t] = a;
    __syncthreads();
    for (int off = 128; off; off >>= 1) {
        if (t < off) s[t] += s[t + off];
        __syncthreads();
    }
    if (t == 0) out_loss[0] = s[0] * invNT;
}

extern "C" void kernel_launch(void* const* d_in, const int* in_sizes, int n_in,
                              void* d_out, int out_size, void* d_ws, size_t ws_size,
                              hipStream_t stream) {
    const int* user = (const int*)d_in[0];
    const int* item = (const int*)d_in[1];
    const float* rating = (const float*)d_in[2];
    const int* t_user = (const int*)d_in[3];
    const int* t_item = (const int*)d_in[4];
    const float* t_rating = (const float*)d_in[5];
    const float* W_enc = (const float*)d_in[6];
    const float* b_enc = (const float*)d_in[7];
    const float* W1 = (const float*)d_in[8];
    const float* b1 = (const float*)d_in[9];
    const float* W2 = (const float*)d_in[10];
    const float* b2 = (const float*)d_in[11];
    const float* W_dec = (const float*)d_in[12];
    const float* b_dec = (const float*)d_in[13];
    const int N = in_sizes[0];
    const int NT = in_sizes[3];

    char* ws = (char*)d_ws;
    size_t off = 0;
    auto alloc = [&](size_t bytes) {
        void* p = ws + off;
        off = (off + bytes + 255) & ~(size_t)255;
        return p;
    };
    unsigned short* wtb = (unsigned short*)alloc((size_t)NUM_ITEMS * H0 * 2);   // 51.2 MB
    unsigned short* xb = (unsigned short*)alloc((size_t)NUM_USERS * H0 * 2);    // 16 MB
    unsigned short* enc_b = (unsigned short*)alloc((size_t)NUM_USERS * LAT * 2);// 8 MB
    unsigned short* dec_b = (unsigned short*)alloc((size_t)NUM_USERS * H0 * 2); // 16 MB
    unsigned short* w1b = (unsigned short*)alloc((size_t)LAT * H0 * 2);
    unsigned short* w2b = (unsigned short*)alloc((size_t)H0 * LAT * 2);
    int* cnt = (int*)alloc((size_t)NUM_USERS * 4);
    int* offs = (int*)alloc((size_t)NUM_USERS * 4);
    int* cursor = (int*)alloc((size_t)NUM_USERS * 4);
    int* s_item = (int*)alloc((size_t)N * 4);
    float* s_rat = (float*)alloc((size_t)N * 4);
    const int predBlocks = (NT + 15) / 16;   // 16 targets / block (4 waves x 4)
    float* partials = (float*)alloc((size_t)predBlocks * 4);

    float* pred = (float*)d_out;
    float* loss = pred + NT;

    hipMemsetAsync(cnt, 0, (size_t)NUM_USERS * 4, stream);
    transpose_kernel<<<dim3((NUM_ITEMS + 31) / 32, H0 / 32), dim3(32, 8), 0, stream>>>(W_enc, wtb);
    count_kernel<<<(N + 255) / 256, 256, 0, stream>>>(user, cnt, N);
    scan_kernel<<<1, 1024, 0, stream>>>(cnt, offs, cursor);
    scatter_kernel<<<(N + 255) / 256, 256, 0, stream>>>(user, item, rating, cursor, s_item, s_rat, N);
    f2bf_kernel<<<(LAT * H0 + 255) / 256, 256, 0, stream>>>(W1, w1b, LAT * H0);
    f2bf_kernel<<<(H0 * LAT + 255) / 256, 256, 0, stream>>>(W2, w2b, H0 * LAT);
    agg_kernel<<<NUM_USERS, 256, 0, stream>>>(wtb, offs, cursor, s_item, s_rat, b_enc, xb);
    gemm_mfma<<<dim3(NUM_USERS / 128, LAT / 128), 256, 0, stream>>>(xb, w1b, b1, enc_b, LAT, H0);
    gemm_mfma<<<dim3(NUM_USERS / 128, H0 / 128), 256, 0, stream>>>(enc_b, w2b, b2, dec_b, H0, LAT);
    predict_kernel<<<predBlocks, 256, 0, stream>>>(dec_b, W_dec, b_dec, t_user, t_item, t_rating,
                                                   pred, partials, NT);
    loss_reduce<<<1, 256, 0, stream>>>(partials, loss, predBlocks, 1.0f / NT);
}

// Round 3
// 472.841 us; speedup vs baseline: 1.5420x; 1.0064x over previous
//
#include <hip/hip_runtime.h>
#include <hip/hip_bf16.h>
#include <math.h>

#define NUM_ITEMS 50000
#define NUM_USERS 16384
#define ITEM_BINS 50176   // 1024 * 49, padded bin count for the item scan
#define H0 512
#define LAT 256

typedef __attribute__((ext_vector_type(8))) short short8;
typedef __attribute__((ext_vector_type(4))) float floatx4;

__device__ __forceinline__ unsigned short f2bf(float f) {
    union { float f; unsigned i; } u; u.f = f;
    unsigned r = u.i + 0x7fff + ((u.i >> 16) & 1);   // RNE
    return (unsigned short)(r >> 16);
}
__device__ __forceinline__ float bfhi(unsigned v) {
    union { unsigned i; float f; } u; u.i = v & 0xffff0000u; return u.f;
}
__device__ __forceinline__ float bflo(unsigned v) {
    union { unsigned i; float f; } u; u.i = v << 16; return u.f;
}

// ---------------- transpose+cast W_enc [H0][NUM_ITEMS] f32 -> wtb [NUM_ITEMS][H0] bf16 ----------------
__global__ void transpose_kernel(const float* __restrict__ src, unsigned short* __restrict__ dst) {
    __shared__ float tile[32][33];
    int tx = threadIdx.x, ty = threadIdx.y;            // 32 x 8
    int x0 = blockIdx.x * 32, y0 = blockIdx.y * 32;    // x: item dim, y: h dim
    int x = x0 + tx;
    if (x < NUM_ITEMS) {
#pragma unroll
        for (int j = 0; j < 32; j += 8)
            tile[ty + j][tx] = src[(size_t)(y0 + ty + j) * NUM_ITEMS + x];
    }
    __syncthreads();
#pragma unroll
    for (int j = 0; j < 32; j += 8) {
        int it = x0 + ty + j;
        if (it < NUM_ITEMS)
            dst[(size_t)it * H0 + y0 + tx] = f2bf(tile[tx][ty + j]);
    }
}

// ---------------- f32 -> bf16 cast for W1 and W2 in one launch ----------------
__global__ void f2bf2_kernel(const float* __restrict__ a, unsigned short* __restrict__ da,
                             const float* __restrict__ b, unsigned short* __restrict__ db, int n) {
    int i = blockIdx.x * blockDim.x + threadIdx.x;
    if (i < n) da[i] = f2bf(a[i]);
    else { int j = i - n; if (j < n) db[j] = f2bf(b[j]); }
}

// ---------------- fused counting: interactions by user, targets by item ----------------
__global__ void count_kernel(const int* __restrict__ user, int* __restrict__ cntU,
                             const int* __restrict__ t_item, int* __restrict__ cntI,
                             int n, int nt) {
    int i = blockIdx.x * blockDim.x + threadIdx.x;
    if (i < n) atomicAdd(&cntU[user[i]], 1);
    if (i < nt) atomicAdd(&cntI[t_item[i]], 1);
}

// two-pass exclusive scan over per*1024 bins; block 0 = users, block 1 = items
__device__ void scan_block(const int* __restrict__ cnt, int* __restrict__ offs,
                           int* __restrict__ cursor, int per) {
    __shared__ int ssum[1024];
    int t = threadIdx.x;
    int base = t * per;
    int s = 0;
    for (int j = 0; j < per; ++j) s += cnt[base + j];
    ssum[t] = s;
    __syncthreads();
    for (int off = 1; off < 1024; off <<= 1) {
        int v = (t >= off) ? ssum[t - off] : 0;
        __syncthreads();
        ssum[t] += v;
        __syncthreads();
    }
    int run = (t == 0) ? 0 : ssum[t - 1];
    for (int j = 0; j < per; ++j) {
        offs[base + j] = run;
        cursor[base + j] = run;
        run += cnt[base + j];
    }
}

__global__ void scan_kernel(const int* __restrict__ cntU, int* __restrict__ offsU, int* __restrict__ curU,
                            const int* __restrict__ cntI, int* __restrict__ offsI, int* __restrict__ curI) {
    if (blockIdx.x == 0) scan_block(cntU, offsU, curU, NUM_USERS / 1024);
    else scan_block(cntI, offsI, curI, ITEM_BINS / 1024);
}

// fused scatter: interactions sorted by user; targets sorted by item (payload: user, rating, orig idx)
__global__ void scatter_kernel(const int* __restrict__ user, const int* __restrict__ item,
                               const float* __restrict__ rating, int* __restrict__ curU,
                               int* __restrict__ s_item, float* __restrict__ s_rat,
                               const int* __restrict__ t_user, const int* __restrict__ t_item,
                               const float* __restrict__ t_rating, int* __restrict__ curI,
                               int* __restrict__ st_user, int* __restrict__ st_item,
                               float* __restrict__ st_rat, int* __restrict__ st_idx,
                               int n, int nt) {
    int i = blockIdx.x * blockDim.x + threadIdx.x;
    if (i < n) {
        int u = user[i];
        int pos = atomicAdd(&curU[u], 1);
        s_item[pos] = item[i];
        s_rat[pos] = rating[i];
    }
    if (i < nt) {
        int it = t_item[i];
        int pos = atomicAdd(&curI[it], 1);
        st_user[pos] = t_user[i];
        st_item[pos] = it;
        st_rat[pos] = t_rating[i];
        st_idx[pos] = i;
    }
}

// ---------------- per-user segment sum + bias + tanh -> xb [NUM_USERS][H0] bf16 ----------------
__global__ __launch_bounds__(256) void agg_kernel(const unsigned short* __restrict__ wtb,
                                                  const int* __restrict__ offs,
                                                  const int* __restrict__ ends,
                                                  const int* __restrict__ s_item,
                                                  const float* __restrict__ s_rat,
                                                  const float* __restrict__ b_enc,
                                                  unsigned short* __restrict__ xb) {
    __shared__ float red[3 * 512];
    int u = blockIdx.x;
    int tid = threadIdx.x;
    int g = tid >> 6, lane = tid & 63;
    float acc[8] = {};
    int j0 = offs[u], j1 = ends[u];
    for (int j = j0 + g; j < j1; j += 4) {
        int it = s_item[j];
        float r = s_rat[j];
        uint4 v = ((const uint4*)(wtb + (size_t)it * H0))[lane];
        acc[0] += bflo(v.x) * r; acc[1] += bfhi(v.x) * r;
        acc[2] += bflo(v.y) * r; acc[3] += bfhi(v.y) * r;
        acc[4] += bflo(v.z) * r; acc[5] += bfhi(v.z) * r;
        acc[6] += bflo(v.w) * r; acc[7] += bfhi(v.w) * r;
    }
    if (g) {
        float4* rp = (float4*)red + (size_t)(g - 1) * 128 + lane * 2;
        rp[0] = make_float4(acc[0], acc[1], acc[2], acc[3]);
        rp[1] = make_float4(acc[4], acc[5], acc[6], acc[7]);
    }
    __syncthreads();
    if (g == 0) {
#pragma unroll
        for (int h = 0; h < 3; ++h) {
            const float* rp = red + h * 512 + lane * 8;
#pragma unroll
            for (int e = 0; e < 8; ++e) acc[e] += rp[e];
        }
        float4 b0 = ((const float4*)b_enc)[lane * 2];
        float4 b1 = ((const float4*)b_enc)[lane * 2 + 1];
        unsigned short o[8];
        o[0] = f2bf(tanhf(acc[0] + b0.x)); o[1] = f2bf(tanhf(acc[1] + b0.y));
        o[2] = f2bf(tanhf(acc[2] + b0.z)); o[3] = f2bf(tanhf(acc[3] + b0.w));
        o[4] = f2bf(tanhf(acc[4] + b1.x)); o[5] = f2bf(tanhf(acc[5] + b1.y));
        o[6] = f2bf(tanhf(acc[6] + b1.z)); o[7] = f2bf(tanhf(acc[7] + b1.w));
        uint4 pk;
        pk.x = (unsigned)o[0] | ((unsigned)o[1] << 16);
        pk.y = (unsigned)o[2] | ((unsigned)o[3] << 16);
        pk.z = (unsigned)o[4] | ((unsigned)o[5] << 16);
        pk.w = (unsigned)o[6] | ((unsigned)o[7] << 16);
        ((uint4*)(xb + (size_t)u * H0))[lane] = pk;
    }
}

// ---------------- bf16 MFMA GEMM: C[m][n] = tanh(bias[n] + sum_k A[m][k]*B[n][k]) -> bf16 ----------------
__global__ __launch_bounds__(256) void gemm_mfma(const unsigned short* __restrict__ A,
                                                 const unsigned short* __restrict__ B,
                                                 const float* __restrict__ bias,
                                                 unsigned short* __restrict__ C,
                                                 int Nn, int K) {
    __shared__ unsigned short Ash[128 * 32];
    __shared__ unsigned short Bsh[128 * 32];
    int tid = threadIdx.x;
    int wid = tid >> 6, lane = tid & 63;
    int wave_m = wid & 1, wave_n = wid >> 1;
    int quad = lane >> 4, l16 = lane & 15;
    int m0 = blockIdx.x * 128, n0 = blockIdx.y * 128;
    floatx4 acc[4][4] = {};

    int srow = lane >> 2;
    int scol = (lane & 3) * 8;
    for (int k0 = 0; k0 < K; k0 += 32) {
#pragma unroll
        for (int i = 0; i < 2; ++i) {
            int c = wid * 2 + i;
            int row = c * 16 + srow;
            const unsigned short* ga = A + (size_t)(m0 + row) * K + k0 + scol;
            const unsigned short* gb = B + (size_t)(n0 + row) * K + k0 + scol;
            __builtin_amdgcn_global_load_lds(
                (const __attribute__((address_space(1))) void*)ga,
                (__attribute__((address_space(3))) void*)((__attribute__((address_space(3))) char*)Ash + c * 1024),
                16, 0, 0);
            __builtin_amdgcn_global_load_lds(
                (const __attribute__((address_space(1))) void*)gb,
                (__attribute__((address_space(3))) void*)((__attribute__((address_space(3))) char*)Bsh + c * 1024),
                16, 0, 0);
        }
        __syncthreads();
        short8 af[4], bfr[4];
#pragma unroll
        for (int i = 0; i < 4; ++i) {
            int ml = wave_m * 64 + i * 16 + l16;
            af[i] = ((const short8*)Ash)[ml * 4 + quad];
            int nl = wave_n * 64 + i * 16 + l16;
            bfr[i] = ((const short8*)Bsh)[nl * 4 + quad];
        }
#pragma unroll
        for (int i = 0; i < 4; ++i)
#pragma unroll
            for (int j = 0; j < 4; ++j)
                acc[i][j] = __builtin_amdgcn_mfma_f32_16x16x32_bf16(af[i], bfr[j], acc[i][j], 0, 0, 0);
        __syncthreads();
    }
#pragma unroll
    for (int j = 0; j < 4; ++j) {
        int col = n0 + wave_n * 64 + j * 16 + l16;
        float bv = bias[col];
#pragma unroll
        for (int i = 0; i < 4; ++i) {
            int rowb = m0 + wave_m * 64 + i * 16 + quad * 4;
#pragma unroll
            for (int r = 0; r < 4; ++r)
                C[(size_t)(rowb + r) * Nn + col] = f2bf(tanhf(acc[i][j][r] + bv));
        }
    }
}

// ---------------- predict over item-sorted targets; scattered write by orig idx ----------------
__global__ __launch_bounds__(256) void predict_kernel(const unsigned short* __restrict__ dec_b,
                                                      const float* __restrict__ W_dec,
                                                      const float* __restrict__ b_dec,
                                                      const int* __restrict__ st_user,
                                                      const int* __restrict__ st_item,
                                                      const float* __restrict__ st_rat,
                                                      const int* __restrict__ st_idx,
                                                      float* __restrict__ pred,
                                                      float* __restrict__ partials, int NT) {
    __shared__ float wsum[4];
    int wid = threadIdx.x >> 6, lane = threadIdx.x & 63;
    int base = (blockIdx.x * 4 + wid) * 4;
    float sq = 0.f;
    int tu[4], ti[4];
    uint4 gv[4];
    float4 wv0[4], wv1[4];
#pragma unroll
    for (int t = 0; t < 4; ++t) {
        int idx = min(base + t, NT - 1);
        tu[t] = st_user[idx];
        ti[t] = st_item[idx];
    }
#pragma unroll
    for (int t = 0; t < 4; ++t) {
        gv[t] = ((const uint4*)(dec_b + (size_t)tu[t] * H0))[lane];
        const float4* w = (const float4*)(W_dec + (size_t)ti[t] * H0);
        wv0[t] = w[lane * 2];
        wv1[t] = w[lane * 2 + 1];
    }
#pragma unroll
    for (int t = 0; t < 4; ++t) {
        float s = bflo(gv[t].x) * wv0[t].x + bfhi(gv[t].x) * wv0[t].y
                + bflo(gv[t].y) * wv0[t].z + bfhi(gv[t].y) * wv0[t].w
                + bflo(gv[t].z) * wv1[t].x + bfhi(gv[t].z) * wv1[t].y
                + bflo(gv[t].w) * wv1[t].z + bfhi(gv[t].w) * wv1[t].w;
#pragma unroll
        for (int off = 32; off; off >>= 1) s += __shfl_xor(s, off, 64);
        if (lane == 0 && base + t < NT) {
            int idx = base + t;
            float p = s + b_dec[ti[t]];
            pred[st_idx[idx]] = p;
            float d = p - st_rat[idx];
            sq += d * d;
        }
    }
    if (lane == 0) wsum[wid] = sq;
    __syncthreads();
    if (threadIdx.x == 0) partials[blockIdx.x] = wsum[0] + wsum[1] + wsum[2] + wsum[3];
}

__global__ void loss_reduce(const float* __restrict__ partials, float* __restrict__ out_loss,
                            int nPart, float invNT) {
    __shared__ float s[256];
    int t = threadIdx.x;
    float a = 0.f;
    for (int i = t; i < nPart; i += 256) a += partials[i];
    s[t] = a;
    __syncthreads();
    for (int off = 128; off; off >>= 1) {
        if (t < off) s[t] += s[t + off];
        __syncthreads();
    }
    if (t == 0) out_loss[0] = s[0] * invNT;
}

extern "C" void kernel_launch(void* const* d_in, const int* in_sizes, int n_in,
                              void* d_out, int out_size, void* d_ws, size_t ws_size,
                              hipStream_t stream) {
    const int* user = (const int*)d_in[0];
    const int* item = (const int*)d_in[1];
    const float* rating = (const float*)d_in[2];
    const int* t_user = (const int*)d_in[3];
    const int* t_item = (const int*)d_in[4];
    const float* t_rating = (const float*)d_in[5];
    const float* W_enc = (const float*)d_in[6];
    const float* b_enc = (const float*)d_in[7];
    const float* W1 = (const float*)d_in[8];
    const float* b1 = (const float*)d_in[9];
    const float* W2 = (const float*)d_in[10];
    const float* b2 = (const float*)d_in[11];
    const float* W_dec = (const float*)d_in[12];
    const float* b_dec = (const float*)d_in[13];
    const int N = in_sizes[0];
    const int NT = in_sizes[3];

    char* ws = (char*)d_ws;
    size_t off = 0;
    auto alloc = [&](size_t bytes) {
        void* p = ws + off;
        off = (off + bytes + 255) & ~(size_t)255;
        return p;
    };
    unsigned short* wtb = (unsigned short*)alloc((size_t)NUM_ITEMS * H0 * 2);   // 51.2 MB
    unsigned short* xb = (unsigned short*)alloc((size_t)NUM_USERS * H0 * 2);    // 16 MB
    unsigned short* enc_b = (unsigned short*)alloc((size_t)NUM_USERS * LAT * 2);// 8 MB
    unsigned short* dec_b = (unsigned short*)alloc((size_t)NUM_USERS * H0 * 2); // 16 MB
    unsigned short* w1b = (unsigned short*)alloc((size_t)LAT * H0 * 2);
    unsigned short* w2b = (unsigned short*)alloc((size_t)H0 * LAT * 2);
    int* cntU = (int*)alloc((size_t)(NUM_USERS + ITEM_BINS) * 4);   // contiguous: one memset
    int* cntI = cntU + NUM_USERS;
    int* offsU = (int*)alloc((size_t)NUM_USERS * 4);
    int* curU = (int*)alloc((size_t)NUM_USERS * 4);
    int* offsI = (int*)alloc((size_t)ITEM_BINS * 4);
    int* curI = (int*)alloc((size_t)ITEM_BINS * 4);
    int* s_item = (int*)alloc((size_t)N * 4);
    float* s_rat = (float*)alloc((size_t)N * 4);
    int* st_user = (int*)alloc((size_t)NT * 4);
    int* st_item = (int*)alloc((size_t)NT * 4);
    float* st_rat = (float*)alloc((size_t)NT * 4);
    int* st_idx = (int*)alloc((size_t)NT * 4);
    const int predBlocks = (NT + 15) / 16;
    float* partials = (float*)alloc((size_t)predBlocks * 4);

    float* pred = (float*)d_out;
    float* loss = pred + NT;

    const int maxNNT = N > NT ? N : NT;
    hipMemsetAsync(cntU, 0, (size_t)(NUM_USERS + ITEM_BINS) * 4, stream);
    count_kernel<<<(maxNNT + 255) / 256, 256, 0, stream>>>(user, cntU, t_item, cntI, N, NT);
    scan_kernel<<<2, 1024, 0, stream>>>(cntU, offsU, curU, cntI, offsI, curI);
    scatter_kernel<<<(maxNNT + 255) / 256, 256, 0, stream>>>(
        user, item, rating, curU, s_item, s_rat,
        t_user, t_item, t_rating, curI, st_user, st_item, st_rat, st_idx, N, NT);
    transpose_kernel<<<dim3((NUM_ITEMS + 31) / 32, H0 / 32), dim3(32, 8), 0, stream>>>(W_enc, wtb);
    f2bf2_kernel<<<(2 * LAT * H0 + 255) / 256, 256, 0, stream>>>(W1, w1b, W2, w2b, LAT * H0);
    agg_kernel<<<NUM_USERS, 256, 0, stream>>>(wtb, offsU, curU, s_item, s_rat, b_enc, xb);
    gemm_mfma<<<dim3(NUM_USERS / 128, LAT / 128), 256, 0, stream>>>(xb, w1b, b1, enc_b, LAT, H0);
    gemm_mfma<<<dim3(NUM_USERS / 128, H0 / 128), 256, 0, stream>>>(enc_b, w2b, b2, dec_b, H0, LAT);
    predict_kernel<<<predBlocks, 256, 0, stream>>>(dec_b, W_dec, b_dec, st_user, st_item, st_rat,
                                                   st_idx, pred, partials, NT);
    loss_reduce<<<1, 256, 0, stream>>>(partials, loss, predBlocks, 1.0f / NT);
}

// Round 4
// 463.430 us; speedup vs baseline: 1.5733x; 1.0203x over previous
//
#include <hip/hip_runtime.h>
#include <hip/hip_bf16.h>
#include <math.h>

#define NUM_ITEMS 50000
#define NUM_USERS 16384
#define ITEM_BINS 65536   // padded bin count for the item scan (per-thread 64, int4-friendly)
#define H0 512
#define LAT 256

typedef __attribute__((ext_vector_type(8))) short short8;
typedef __attribute__((ext_vector_type(4))) float floatx4;

__device__ __forceinline__ unsigned short f2bf(float f) {
    union { float f; unsigned i; } u; u.f = f;
    unsigned r = u.i + 0x7fff + ((u.i >> 16) & 1);   // RNE
    return (unsigned short)(r >> 16);
}
__device__ __forceinline__ float bfhi(unsigned v) {
    union { unsigned i; float f; } u; u.i = v & 0xffff0000u; return u.f;
}
__device__ __forceinline__ float bflo(unsigned v) {
    union { unsigned i; float f; } u; u.i = v << 16; return u.f;
}
__device__ __forceinline__ uint4 pack8(const float* v) {
    uint4 p;
    p.x = (unsigned)f2bf(v[0]) | ((unsigned)f2bf(v[1]) << 16);
    p.y = (unsigned)f2bf(v[2]) | ((unsigned)f2bf(v[3]) << 16);
    p.z = (unsigned)f2bf(v[4]) | ((unsigned)f2bf(v[5]) << 16);
    p.w = (unsigned)f2bf(v[6]) | ((unsigned)f2bf(v[7]) << 16);
    return p;
}

// ================= mega-fused setup: count atomics + transpose + casts =================
// block ranges: [0,TB) transpose W_enc->wtb ; [TB,TB+DB) W_dec cast ; [TB+DB, +CB) counting ;
// [TB+DB+CB, +WB) W1/W2 cast.
__global__ __launch_bounds__(256) void setup_kernel(
        const float* __restrict__ W_enc, unsigned short* __restrict__ wtb,
        const float* __restrict__ W_dec, unsigned short* __restrict__ wdb,
        const float* __restrict__ W1, unsigned short* __restrict__ w1b,
        const float* __restrict__ W2, unsigned short* __restrict__ w2b,
        const int* __restrict__ user, int* __restrict__ cntU,
        const int* __restrict__ t_item, int* __restrict__ cntI,
        int n, int nt, int TB, int DB, int CB) {
    __shared__ float tile[64][65];
    int bid = blockIdx.x;
    int tid = threadIdx.x;
    if (bid < TB) {
        // ---- transpose+cast W_enc [H0][NUM_ITEMS] -> wtb [NUM_ITEMS][H0], 64x64 tiles ----
        const int TBX = (NUM_ITEMS + 63) / 64;
        int bx = bid % TBX, by = bid / TBX;
        int x0 = bx * 64, y0 = by * 64;        // x: item, y: h
        int tx = tid & 63, ty = tid >> 6;      // 64 x 4
        int x = x0 + tx;
        if (x < NUM_ITEMS) {
#pragma unroll
            for (int j = 0; j < 64; j += 4)
                tile[j + ty][tx] = W_enc[(size_t)(y0 + j + ty) * NUM_ITEMS + x];
        }
        __syncthreads();
#pragma unroll
        for (int j = 0; j < 64; j += 4) {
            int it = x0 + j + ty;
            if (it < NUM_ITEMS)
                wtb[(size_t)it * H0 + y0 + tx] = f2bf(tile[tx][j + ty]);
        }
    } else if (bid < TB + DB) {
        // ---- W_dec [NUM_ITEMS*H0] f32 -> bf16, 8 elems/thread ----
        int idx = (bid - TB) * 2048 + tid * 8;
        float v[8];
        *(float4*)&v[0] = *(const float4*)(W_dec + idx);
        *(float4*)&v[4] = *(const float4*)(W_dec + idx + 4);
        *(uint4*)(wdb + idx) = pack8(v);
    } else if (bid < TB + DB + CB) {
        // ---- histogram users (interactions) and items (targets) ----
        int i = (bid - TB - DB) * 1024 + tid * 4;
        if (i + 3 < n) {
            int4 u = *(const int4*)(user + i);
            atomicAdd(&cntU[u.x], 1); atomicAdd(&cntU[u.y], 1);
            atomicAdd(&cntU[u.z], 1); atomicAdd(&cntU[u.w], 1);
        } else {
            for (int k = i; k < n; ++k) atomicAdd(&cntU[user[k]], 1);
        }
        if (i + 3 < nt) {
            int4 t = *(const int4*)(t_item + i);
            atomicAdd(&cntI[t.x], 1); atomicAdd(&cntI[t.y], 1);
            atomicAdd(&cntI[t.z], 1); atomicAdd(&cntI[t.w], 1);
        } else {
            for (int k = i; k < nt; ++k) atomicAdd(&cntI[t_item[k]], 1);
        }
    } else {
        // ---- W1 / W2 cast, 64 blocks each ----
        int b2i = bid - TB - DB - CB;
        const float* src = (b2i < 64) ? W1 : W2;
        unsigned short* dst = (b2i < 64) ? w1b : w2b;
        int idx = (b2i & 63) * 2048 + tid * 8;
        float v[8];
        *(float4*)&v[0] = *(const float4*)(src + idx);
        *(float4*)&v[4] = *(const float4*)(src + idx + 4);
        *(uint4*)(dst + idx) = pack8(v);
    }
}

// ================= dual exclusive scan (block0: users per=16, block1: items per=64) =================
__device__ void scan_block(const int* __restrict__ cnt, int* __restrict__ offs,
                           int* __restrict__ cursor, int per) {
    __shared__ int ssum[1024];
    int t = threadIdx.x;
    int base = t * per;
    int s = 0;
    for (int j = 0; j < per; j += 4) {
        int4 v = *(const int4*)(cnt + base + j);
        s += v.x + v.y + v.z + v.w;
    }
    ssum[t] = s;
    __syncthreads();
    for (int off = 1; off < 1024; off <<= 1) {
        int v = (t >= off) ? ssum[t - off] : 0;
        __syncthreads();
        ssum[t] += v;
        __syncthreads();
    }
    int run = (t == 0) ? 0 : ssum[t - 1];
    for (int j = 0; j < per; j += 4) {
        int4 v = *(const int4*)(cnt + base + j);
        int4 o;
        o.x = run; run += v.x;
        o.y = run; run += v.y;
        o.z = run; run += v.z;
        o.w = run; run += v.w;
        *(int4*)(offs + base + j) = o;
        *(int4*)(cursor + base + j) = o;
    }
}

__global__ void scan_kernel(const int* __restrict__ cntU, int* __restrict__ offsU, int* __restrict__ curU,
                            const int* __restrict__ cntI, int* __restrict__ offsI, int* __restrict__ curI) {
    if (blockIdx.x == 0) scan_block(cntU, offsU, curU, NUM_USERS / 1024);
    else scan_block(cntI, offsI, curI, ITEM_BINS / 1024);
}

// ================= fused scatter: interactions by user (int2), targets by item (int4) =================
__global__ void scatter_kernel(const int* __restrict__ user, const int* __restrict__ item,
                               const float* __restrict__ rating, int* __restrict__ curU,
                               int2* __restrict__ s_pack,
                               const int* __restrict__ t_user, const int* __restrict__ t_item,
                               const float* __restrict__ t_rating, int* __restrict__ curI,
                               int4* __restrict__ st_pack, int n, int nt) {
    int i = blockIdx.x * blockDim.x + threadIdx.x;
    if (i < n) {
        int u = user[i];
        int pos = atomicAdd(&curU[u], 1);
        s_pack[pos] = make_int2(item[i], __float_as_int(rating[i]));
    }
    if (i < nt) {
        int it = t_item[i];
        int pos = atomicAdd(&curI[it], 1);
        st_pack[pos] = make_int4(t_user[i], it, __float_as_int(t_rating[i]), i);
    }
}

// ================= per-user segment sum + bias + tanh -> xb bf16 =================
__global__ __launch_bounds__(256) void agg_kernel(const unsigned short* __restrict__ wtb,
                                                  const int* __restrict__ offs,
                                                  const int* __restrict__ ends,
                                                  const int2* __restrict__ s_pack,
                                                  const float* __restrict__ b_enc,
                                                  unsigned short* __restrict__ xb) {
    __shared__ float red[3 * 512];
    int u = blockIdx.x;
    int tid = threadIdx.x;
    int g = tid >> 6, lane = tid & 63;
    float acc[8] = {};
    int j0 = offs[u], j1 = ends[u];
    int j = j0 + g;
    int2 nxt = (j < j1) ? s_pack[j] : make_int2(0, 0);
    while (j < j1) {
        int2 cur = nxt;
        int jn = j + 4;
        if (jn < j1) nxt = s_pack[jn];
        float r = __int_as_float(cur.y);
        uint4 v = ((const uint4*)(wtb + (size_t)cur.x * H0))[lane];
        acc[0] += bflo(v.x) * r; acc[1] += bfhi(v.x) * r;
        acc[2] += bflo(v.y) * r; acc[3] += bfhi(v.y) * r;
        acc[4] += bflo(v.z) * r; acc[5] += bfhi(v.z) * r;
        acc[6] += bflo(v.w) * r; acc[7] += bfhi(v.w) * r;
        j = jn;
    }
    if (g) {
        float4* rp = (float4*)red + (size_t)(g - 1) * 128 + lane * 2;
        rp[0] = make_float4(acc[0], acc[1], acc[2], acc[3]);
        rp[1] = make_float4(acc[4], acc[5], acc[6], acc[7]);
    }
    __syncthreads();
    if (g == 0) {
#pragma unroll
        for (int h = 0; h < 3; ++h) {
            const float* rp = red + h * 512 + lane * 8;
#pragma unroll
            for (int e = 0; e < 8; ++e) acc[e] += rp[e];
        }
        float4 b0 = ((const float4*)b_enc)[lane * 2];
        float4 b1 = ((const float4*)b_enc)[lane * 2 + 1];
        float o[8];
        o[0] = tanhf(acc[0] + b0.x); o[1] = tanhf(acc[1] + b0.y);
        o[2] = tanhf(acc[2] + b0.z); o[3] = tanhf(acc[3] + b0.w);
        o[4] = tanhf(acc[4] + b1.x); o[5] = tanhf(acc[5] + b1.y);
        o[6] = tanhf(acc[6] + b1.z); o[7] = tanhf(acc[7] + b1.w);
        ((uint4*)(xb + (size_t)u * H0))[lane] = pack8(o);
    }
}

// ================= bf16 MFMA GEMM, 128 x BN tile, tanh epilogue =================
template<int BN>
__global__ __launch_bounds__(256) void gemm_mfma(const unsigned short* __restrict__ A,
                                                 const unsigned short* __restrict__ B,
                                                 const float* __restrict__ bias,
                                                 unsigned short* __restrict__ C,
                                                 int Nn, int K) {
    constexpr int WN = BN / 32;        // n-frags per wave
    constexpr int NCH = 8 + BN / 16;   // total 16-row staging chunks (A:8, B:BN/16)
    constexpr int PER = NCH / 4;       // chunks per wave
    __shared__ unsigned short Ash[128 * 32];
    __shared__ unsigned short Bsh[BN * 32];
    int tid = threadIdx.x;
    int wid = tid >> 6, lane = tid & 63;
    int wave_m = wid & 1, wave_n = wid >> 1;
    int quad = lane >> 4, l16 = lane & 15;
    int m0 = blockIdx.x * 128, n0 = blockIdx.y * BN;
    floatx4 acc[4][WN] = {};
    int srow = lane >> 2;
    int scol = (lane & 3) * 8;
    for (int k0 = 0; k0 < K; k0 += 32) {
#pragma unroll
        for (int i = 0; i < PER; ++i) {
            int c = wid * PER + i;
            if (c < 8) {
                const unsigned short* ga = A + (size_t)(m0 + c * 16 + srow) * K + k0 + scol;
                __builtin_amdgcn_global_load_lds(
                    (const __attribute__((address_space(1))) void*)ga,
                    (__attribute__((address_space(3))) void*)((__attribute__((address_space(3))) char*)Ash + c * 1024),
                    16, 0, 0);
            } else {
                const unsigned short* gb = B + (size_t)(n0 + (c - 8) * 16 + srow) * K + k0 + scol;
                __builtin_amdgcn_global_load_lds(
                    (const __attribute__((address_space(1))) void*)gb,
                    (__attribute__((address_space(3))) void*)((__attribute__((address_space(3))) char*)Bsh + (c - 8) * 1024),
                    16, 0, 0);
            }
        }
        __syncthreads();
        short8 af[4], bfr[WN];
#pragma unroll
        for (int i = 0; i < 4; ++i) {
            int ml = wave_m * 64 + i * 16 + l16;
            af[i] = ((const short8*)Ash)[ml * 4 + quad];
        }
#pragma unroll
        for (int j = 0; j < WN; ++j) {
            int nl = wave_n * (BN / 2) + j * 16 + l16;
            bfr[j] = ((const short8*)Bsh)[nl * 4 + quad];
        }
#pragma unroll
        for (int i = 0; i < 4; ++i)
#pragma unroll
            for (int j = 0; j < WN; ++j)
                acc[i][j] = __builtin_amdgcn_mfma_f32_16x16x32_bf16(af[i], bfr[j], acc[i][j], 0, 0, 0);
        __syncthreads();
    }
#pragma unroll
    for (int j = 0; j < WN; ++j) {
        int col = n0 + wave_n * (BN / 2) + j * 16 + l16;
        float bv = bias[col];
#pragma unroll
        for (int i = 0; i < 4; ++i) {
            int rowb = m0 + wave_m * 64 + i * 16 + quad * 4;
#pragma unroll
            for (int r = 0; r < 4; ++r)
                C[(size_t)(rowb + r) * Nn + col] = f2bf(tanhf(acc[i][j][r] + bv));
        }
    }
}

// ================= predict over item-sorted packed targets =================
__global__ __launch_bounds__(256) void predict_kernel(const unsigned short* __restrict__ dec_b,
                                                      const unsigned short* __restrict__ wdb,
                                                      const float* __restrict__ b_dec,
                                                      const int4* __restrict__ st,
                                                      float* __restrict__ pred,
                                                      float* __restrict__ partials, int NT) {
    __shared__ float wsum[4];
    int wid = threadIdx.x >> 6, lane = threadIdx.x & 63;
    int base = (blockIdx.x * 4 + wid) * 4;
    float sq = 0.f;
    int4 tv[4];
    uint4 gv[4], wv[4];
#pragma unroll
    for (int t = 0; t < 4; ++t) tv[t] = st[min(base + t, NT - 1)];
#pragma unroll
    for (int t = 0; t < 4; ++t) {
        gv[t] = ((const uint4*)(dec_b + (size_t)tv[t].x * H0))[lane];
        wv[t] = ((const uint4*)(wdb + (size_t)tv[t].y * H0))[lane];
    }
#pragma unroll
    for (int t = 0; t < 4; ++t) {
        float s = bflo(gv[t].x) * bflo(wv[t].x) + bfhi(gv[t].x) * bfhi(wv[t].x)
                + bflo(gv[t].y) * bflo(wv[t].y) + bfhi(gv[t].y) * bfhi(wv[t].y)
                + bflo(gv[t].z) * bflo(wv[t].z) + bfhi(gv[t].z) * bfhi(wv[t].z)
                + bflo(gv[t].w) * bflo(wv[t].w) + bfhi(gv[t].w) * bfhi(wv[t].w);
#pragma unroll
        for (int off = 32; off; off >>= 1) s += __shfl_xor(s, off, 64);
        if (lane == 0 && base + t < NT) {
            float p = s + b_dec[tv[t].y];
            pred[tv[t].w] = p;
            float d = p - __int_as_float(tv[t].z);
            sq += d * d;
        }
    }
    if (lane == 0) wsum[wid] = sq;
    __syncthreads();
    if (threadIdx.x == 0) partials[blockIdx.x] = wsum[0] + wsum[1] + wsum[2] + wsum[3];
}

__global__ void loss_reduce(const float* __restrict__ partials, float* __restrict__ out_loss,
                            int nPart, float invNT) {
    __shared__ float s[256];
    int t = threadIdx.x;
    float a = 0.f;
    const float4* p4 = (const float4*)partials;
    int n4 = nPart >> 2;
    for (int i = t; i < n4; i += 256) {
        float4 v = p4[i];
        a += v.x + v.y + v.z + v.w;
    }
    for (int i = (n4 << 2) + t; i < nPart; i += 256) a += partials[i];
    s[t] = a;
    __syncthreads();
    for (int off = 128; off; off >>= 1) {
        if (t < off) s[t] += s[t + off];
        __syncthreads();
    }
    if (t == 0) out_loss[0] = s[0] * invNT;
}

extern "C" void kernel_launch(void* const* d_in, const int* in_sizes, int n_in,
                              void* d_out, int out_size, void* d_ws, size_t ws_size,
                              hipStream_t stream) {
    const int* user = (const int*)d_in[0];
    const int* item = (const int*)d_in[1];
    const float* rating = (const float*)d_in[2];
    const int* t_user = (const int*)d_in[3];
    const int* t_item = (const int*)d_in[4];
    const float* t_rating = (const float*)d_in[5];
    const float* W_enc = (const float*)d_in[6];
    const float* b_enc = (const float*)d_in[7];
    const float* W1 = (const float*)d_in[8];
    const float* b1 = (const float*)d_in[9];
    const float* W2 = (const float*)d_in[10];
    const float* b2 = (const float*)d_in[11];
    const float* W_dec = (const float*)d_in[12];
    const float* b_dec = (const float*)d_in[13];
    const int N = in_sizes[0];
    const int NT = in_sizes[3];

    char* ws = (char*)d_ws;
    size_t off = 0;
    auto alloc = [&](size_t bytes) {
        void* p = ws + off;
        off = (off + bytes + 255) & ~(size_t)255;
        return p;
    };
    unsigned short* wtb = (unsigned short*)alloc((size_t)NUM_ITEMS * H0 * 2);   // 51.2 MB
    unsigned short* wdb = (unsigned short*)alloc((size_t)NUM_ITEMS * H0 * 2);   // 51.2 MB
    unsigned short* xb = (unsigned short*)alloc((size_t)NUM_USERS * H0 * 2);    // 16 MB
    unsigned short* enc_b = (unsigned short*)alloc((size_t)NUM_USERS * LAT * 2);// 8 MB
    unsigned short* dec_b = (unsigned short*)alloc((size_t)NUM_USERS * H0 * 2); // 16 MB
    unsigned short* w1b = (unsigned short*)alloc((size_t)LAT * H0 * 2);
    unsigned short* w2b = (unsigned short*)alloc((size_t)H0 * LAT * 2);
    int* cntU = (int*)alloc((size_t)(NUM_USERS + ITEM_BINS) * 4);   // contiguous: one memset
    int* cntI = cntU + NUM_USERS;
    int* offsU = (int*)alloc((size_t)NUM_USERS * 4);
    int* curU = (int*)alloc((size_t)NUM_USERS * 4);
    int* offsI = (int*)alloc((size_t)ITEM_BINS * 4);
    int* curI = (int*)alloc((size_t)ITEM_BINS * 4);
    int2* s_pack = (int2*)alloc((size_t)N * 8);
    int4* st_pack = (int4*)alloc((size_t)NT * 16);
    const int predBlocks = (NT + 15) / 16;
    float* partials = (float*)alloc((size_t)predBlocks * 4);

    float* pred = (float*)d_out;
    float* loss = pred + NT;

    const int maxNNT = N > NT ? N : NT;
    const int TBX = (NUM_ITEMS + 63) / 64;         // 782
    const int TB = TBX * (H0 / 64);                // 6256 transpose blocks
    const int DB = (NUM_ITEMS * H0) / 2048;        // 12500 W_dec cast blocks
    const int CB = (maxNNT + 1023) / 1024;         // 256 count blocks
    const int WB = 128;                            // W1+W2 cast blocks

    hipMemsetAsync(cntU, 0, (size_t)(NUM_USERS + ITEM_BINS) * 4, stream);
    setup_kernel<<<TB + DB + CB + WB, 256, 0, stream>>>(
        W_enc, wtb, W_dec, wdb, W1, w1b, W2, w2b,
        user, cntU, t_item, cntI, N, NT, TB, DB, CB);
    scan_kernel<<<2, 1024, 0, stream>>>(cntU, offsU, curU, cntI, offsI, curI);
    scatter_kernel<<<(maxNNT + 255) / 256, 256, 0, stream>>>(
        user, item, rating, curU, s_pack,
        t_user, t_item, t_rating, curI, st_pack, N, NT);
    agg_kernel<<<NUM_USERS, 256, 0, stream>>>(wtb, offsU, curU, s_pack, b_enc, xb);
    gemm_mfma<64><<<dim3(NUM_USERS / 128, LAT / 64), 256, 0, stream>>>(xb, w1b, b1, enc_b, LAT, H0);
    gemm_mfma<64><<<dim3(NUM_USERS / 128, H0 / 64), 256, 0, stream>>>(enc_b, w2b, b2, dec_b, H0, LAT);
    predict_kernel<<<predBlocks, 256, 0, stream>>>(dec_b, wdb, b_dec, st_pack, pred, partials, NT);
    loss_reduce<<<1, 256, 0, stream>>>(partials, loss, predBlocks, 1.0f / NT);
}

// Round 5
// 450.905 us; speedup vs baseline: 1.6170x; 1.0278x over previous
//
#include <hip/hip_runtime.h>
#include <hip/hip_bf16.h>
#include <math.h>

#define NUM_ITEMS 50000
#define NUM_USERS 16384
#define ITEM_BINS 65536   // padded bin count for the item scan
#define H0 512
#define LAT 256
#define FP8_SCALE 64.0f   // weights ~±0.011 are subnormal in e4m3; x64 -> ~0.7 (3% rel err)
#define FP8_INV (1.0f / 64.0f)

typedef __attribute__((ext_vector_type(8))) short short8;
typedef __attribute__((ext_vector_type(4))) float floatx4;
typedef __attribute__((ext_vector_type(2))) float vf2;

__device__ __forceinline__ unsigned short f2bf(float f) {
    union { float f; unsigned i; } u; u.f = f;
    unsigned r = u.i + 0x7fff + ((u.i >> 16) & 1);   // RNE
    return (unsigned short)(r >> 16);
}
__device__ __forceinline__ float bfhi(unsigned v) {
    union { unsigned i; float f; } u; u.i = v & 0xffff0000u; return u.f;
}
__device__ __forceinline__ float bflo(unsigned v) {
    union { unsigned i; float f; } u; u.i = v << 16; return u.f;
}
__device__ __forceinline__ uint4 pack8(const float* v) {
    uint4 p;
    p.x = (unsigned)f2bf(v[0]) | ((unsigned)f2bf(v[1]) << 16);
    p.y = (unsigned)f2bf(v[2]) | ((unsigned)f2bf(v[3]) << 16);
    p.z = (unsigned)f2bf(v[4]) | ((unsigned)f2bf(v[5]) << 16);
    p.w = (unsigned)f2bf(v[6]) | ((unsigned)f2bf(v[7]) << 16);
    return p;
}
// pack 4 floats -> 4 fp8 e4m3 (OCP on gfx950)
__device__ __forceinline__ unsigned pkfp8_4(float a, float b, float c, float d) {
    int v = __builtin_amdgcn_cvt_pk_fp8_f32(a, b, 0, false);
    v = __builtin_amdgcn_cvt_pk_fp8_f32(c, d, v, true);
    return (unsigned)v;
}
__device__ __forceinline__ void fp8x4_to_f32(unsigned v, float* o) {
    vf2 lo = __builtin_amdgcn_cvt_pk_f32_fp8((int)v, false);
    vf2 hi = __builtin_amdgcn_cvt_pk_f32_fp8((int)v, true);
    o[0] = lo.x; o[1] = lo.y; o[2] = hi.x; o[3] = hi.y;
}

// ================= count: users (interactions) + items (targets) =================
__global__ __launch_bounds__(256) void count_kernel(const int* __restrict__ user, int* __restrict__ cntU,
                                                    const int* __restrict__ t_item, int* __restrict__ cntI,
                                                    int n, int nt) {
    int i = (blockIdx.x * blockDim.x + threadIdx.x) * 4;
    if (i + 3 < n) {
        int4 u = *(const int4*)(user + i);
        atomicAdd(&cntU[u.x], 1); atomicAdd(&cntU[u.y], 1);
        atomicAdd(&cntU[u.z], 1); atomicAdd(&cntU[u.w], 1);
    } else {
        for (int k = i; k < n; ++k) atomicAdd(&cntU[user[k]], 1);
    }
    if (i + 3 < nt) {
        int4 t = *(const int4*)(t_item + i);
        atomicAdd(&cntI[t.x], 1); atomicAdd(&cntI[t.y], 1);
        atomicAdd(&cntI[t.z], 1); atomicAdd(&cntI[t.w], 1);
    } else {
        for (int k = i; k < nt; ++k) atomicAdd(&cntI[t_item[k]], 1);
    }
}

// ================= dual exclusive scan =================
__device__ void scan_block(const int* __restrict__ cnt, int* __restrict__ offs,
                           int* __restrict__ cursor, int per) {
    __shared__ int ssum[1024];
    int t = threadIdx.x;
    int base = t * per;
    int s = 0;
    for (int j = 0; j < per; j += 4) {
        int4 v = *(const int4*)(cnt + base + j);
        s += v.x + v.y + v.z + v.w;
    }
    ssum[t] = s;
    __syncthreads();
    for (int off = 1; off < 1024; off <<= 1) {
        int v = (t >= off) ? ssum[t - off] : 0;
        __syncthreads();
        ssum[t] += v;
        __syncthreads();
    }
    int run = (t == 0) ? 0 : ssum[t - 1];
    for (int j = 0; j < per; j += 4) {
        int4 v = *(const int4*)(cnt + base + j);
        int4 o;
        o.x = run; run += v.x;
        o.y = run; run += v.y;
        o.z = run; run += v.z;
        o.w = run; run += v.w;
        *(int4*)(offs + base + j) = o;
        *(int4*)(cursor + base + j) = o;
    }
}

__global__ void scan_kernel(const int* __restrict__ cntU, int* __restrict__ offsU, int* __restrict__ curU,
                            const int* __restrict__ cntI, int* __restrict__ offsI, int* __restrict__ curI) {
    if (blockIdx.x == 0) scan_block(cntU, offsU, curU, NUM_USERS / 1024);
    else scan_block(cntI, offsI, curI, ITEM_BINS / 1024);
}

// ================= mega kernel: scatter | transpose W_enc -> fp8 | W_dec -> fp8 | W1/W2 -> bf16 =================
// block ranges: [0,SB) scatter ; [SB,SB+TB) transpose ; [SB+TB,+DB) W_dec ; [+WB) W1/W2.
__global__ __launch_bounds__(256) void mega_kernel(
        const int* __restrict__ user, const int* __restrict__ item,
        const float* __restrict__ rating, int* __restrict__ curU, int2* __restrict__ s_pack,
        const int* __restrict__ t_user, const int* __restrict__ t_item,
        const float* __restrict__ t_rating, int* __restrict__ curI, int4* __restrict__ st_pack,
        const float* __restrict__ W_enc, unsigned char* __restrict__ wtb8,
        const float* __restrict__ W_dec, unsigned char* __restrict__ wdb8,
        const float* __restrict__ W1, unsigned short* __restrict__ w1b,
        const float* __restrict__ W2, unsigned short* __restrict__ w2b,
        int n, int nt, int SB, int TB, int DB) {
    __shared__ float tileT[64 * 129];   // [item][h] padded
    int bid = blockIdx.x;
    int tid = threadIdx.x;
    if (bid < SB) {
        // ---- scatter: interactions by user (int2), targets by item (int4) ----
        int i = bid * 256 + tid;
        if (i < n) {
            int u = user[i];
            int pos = atomicAdd(&curU[u], 1);
            s_pack[pos] = make_int2(item[i], __float_as_int(rating[i]));
        }
        if (i < nt) {
            int it = t_item[i];
            int pos = atomicAdd(&curI[it], 1);
            st_pack[pos] = make_int4(t_user[i], it, __float_as_int(t_rating[i]), i);
        }
    } else if (bid < SB + TB) {
        // ---- transpose W_enc [H0][NUM_ITEMS] f32 -> wtb8 [NUM_ITEMS][H0] fp8 (x64), 64it x 128h tiles ----
        const int TBX = (NUM_ITEMS + 63) / 64;   // 782
        int b = bid - SB;
        int x0 = (b % TBX) * 64;        // item base
        int y0 = (b / TBX) * 128;       // h base
        int g = tid >> 4;               // 0..15 h-sub
        int m = tid & 15;               // item quad
        int ibase = m * 4;
#pragma unroll
        for (int p = 0; p < 8; ++p) {
            int hloc = p * 16 + g;
            int it = x0 + ibase;
            if (it < NUM_ITEMS) {
                float4 v = *(const float4*)(W_enc + (size_t)(y0 + hloc) * NUM_ITEMS + it);
                tileT[(ibase + 0) * 129 + hloc] = v.x;
                tileT[(ibase + 1) * 129 + hloc] = v.y;
                tileT[(ibase + 2) * 129 + hloc] = v.z;
                tileT[(ibase + 3) * 129 + hloc] = v.w;
            }
        }
        __syncthreads();
        int l = tid & 7;                // 16-element h chunk
        int i0 = tid >> 3;              // item within pass (32/pass)
#pragma unroll
        for (int p = 0; p < 2; ++p) {
            int i = p * 32 + i0;
            int it = x0 + i;
            if (it < NUM_ITEMS) {
                const float* src = tileT + i * 129 + l * 16;
                uint4 o;
                o.x = pkfp8_4(src[0] * FP8_SCALE, src[1] * FP8_SCALE, src[2] * FP8_SCALE, src[3] * FP8_SCALE);
                o.y = pkfp8_4(src[4] * FP8_SCALE, src[5] * FP8_SCALE, src[6] * FP8_SCALE, src[7] * FP8_SCALE);
                o.z = pkfp8_4(src[8] * FP8_SCALE, src[9] * FP8_SCALE, src[10] * FP8_SCALE, src[11] * FP8_SCALE);
                o.w = pkfp8_4(src[12] * FP8_SCALE, src[13] * FP8_SCALE, src[14] * FP8_SCALE, src[15] * FP8_SCALE);
                *(uint4*)(wtb8 + (size_t)it * H0 + y0 + l * 16) = o;
            }
        }
    } else if (bid < SB + TB + DB) {
        // ---- W_dec f32 -> fp8 (x64), 16 elems/thread ----
        size_t idx = (size_t)(bid - SB - TB) * 4096 + tid * 16;
        float4 v0 = *(const float4*)(W_dec + idx);
        float4 v1 = *(const float4*)(W_dec + idx + 4);
        float4 v2 = *(const float4*)(W_dec + idx + 8);
        float4 v3 = *(const float4*)(W_dec + idx + 12);
        uint4 o;
        o.x = pkfp8_4(v0.x * FP8_SCALE, v0.y * FP8_SCALE, v0.z * FP8_SCALE, v0.w * FP8_SCALE);
        o.y = pkfp8_4(v1.x * FP8_SCALE, v1.y * FP8_SCALE, v1.z * FP8_SCALE, v1.w * FP8_SCALE);
        o.z = pkfp8_4(v2.x * FP8_SCALE, v2.y * FP8_SCALE, v2.z * FP8_SCALE, v2.w * FP8_SCALE);
        o.w = pkfp8_4(v3.x * FP8_SCALE, v3.y * FP8_SCALE, v3.z * FP8_SCALE, v3.w * FP8_SCALE);
        *(uint4*)(wdb8 + idx) = o;
    } else {
        // ---- W1 / W2 cast to bf16, 64 blocks each ----
        int b2i = bid - SB - TB - DB;
        const float* src = (b2i < 64) ? W1 : W2;
        unsigned short* dst = (b2i < 64) ? w1b : w2b;
        int idx = (b2i & 63) * 2048 + tid * 8;
        float v[8];
        *(float4*)&v[0] = *(const float4*)(src + idx);
        *(float4*)&v[4] = *(const float4*)(src + idx + 4);
        *(uint4*)(dst + idx) = pack8(v);
    }
}

// ================= per-user segment sum + bias + tanh -> xb bf16 =================
__global__ __launch_bounds__(256) void agg_kernel(const unsigned char* __restrict__ wtb8,
                                                  const int* __restrict__ offs,
                                                  const int* __restrict__ ends,
                                                  const int2* __restrict__ s_pack,
                                                  const float* __restrict__ b_enc,
                                                  unsigned short* __restrict__ xb) {
    __shared__ float red[3 * 512];
    int u = blockIdx.x;
    int tid = threadIdx.x;
    int g = tid >> 6, lane = tid & 63;
    float acc[8] = {};
    int j0 = offs[u], j1 = ends[u];
    int j = j0 + g;
    int2 nxt = (j < j1) ? s_pack[j] : make_int2(0, 0);
    while (j < j1) {
        int2 cur = nxt;
        int jn = j + 4;
        if (jn < j1) nxt = s_pack[jn];
        float r = __int_as_float(cur.y);
        uint2 v = ((const uint2*)(wtb8 + (size_t)cur.x * H0))[lane];
        float wf[8];
        fp8x4_to_f32(v.x, wf);
        fp8x4_to_f32(v.y, wf + 4);
#pragma unroll
        for (int e = 0; e < 8; ++e) acc[e] += wf[e] * r;
        j = jn;
    }
    if (g) {
        float4* rp = (float4*)red + (size_t)(g - 1) * 128 + lane * 2;
        rp[0] = make_float4(acc[0], acc[1], acc[2], acc[3]);
        rp[1] = make_float4(acc[4], acc[5], acc[6], acc[7]);
    }
    __syncthreads();
    if (g == 0) {
#pragma unroll
        for (int h = 0; h < 3; ++h) {
            const float* rp = red + h * 512 + lane * 8;
#pragma unroll
            for (int e = 0; e < 8; ++e) acc[e] += rp[e];
        }
        float4 b0 = ((const float4*)b_enc)[lane * 2];
        float4 b1 = ((const float4*)b_enc)[lane * 2 + 1];
        float o[8];
        o[0] = tanhf(acc[0] * FP8_INV + b0.x); o[1] = tanhf(acc[1] * FP8_INV + b0.y);
        o[2] = tanhf(acc[2] * FP8_INV + b0.z); o[3] = tanhf(acc[3] * FP8_INV + b0.w);
        o[4] = tanhf(acc[4] * FP8_INV + b1.x); o[5] = tanhf(acc[5] * FP8_INV + b1.y);
        o[6] = tanhf(acc[6] * FP8_INV + b1.z); o[7] = tanhf(acc[7] * FP8_INV + b1.w);
        ((uint4*)(xb + (size_t)u * H0))[lane] = pack8(o);
    }
}

// ================= bf16 MFMA GEMM, 128 x BN tile, tanh epilogue =================
template<int BN>
__global__ __launch_bounds__(256) void gemm_mfma(const unsigned short* __restrict__ A,
                                                 const unsigned short* __restrict__ B,
                                                 const float* __restrict__ bias,
                                                 unsigned short* __restrict__ C,
                                                 int Nn, int K) {
    constexpr int WN = BN / 32;
    constexpr int NCH = 8 + BN / 16;
    constexpr int PER = NCH / 4;
    __shared__ unsigned short Ash[128 * 32];
    __shared__ unsigned short Bsh[BN * 32];
    int tid = threadIdx.x;
    int wid = tid >> 6, lane = tid & 63;
    int wave_m = wid & 1, wave_n = wid >> 1;
    int quad = lane >> 4, l16 = lane & 15;
    int m0 = blockIdx.x * 128, n0 = blockIdx.y * BN;
    floatx4 acc[4][WN] = {};
    int srow = lane >> 2;
    int scol = (lane & 3) * 8;
    for (int k0 = 0; k0 < K; k0 += 32) {
#pragma unroll
        for (int i = 0; i < PER; ++i) {
            int c = wid * PER + i;
            if (c < 8) {
                const unsigned short* ga = A + (size_t)(m0 + c * 16 + srow) * K + k0 + scol;
                __builtin_amdgcn_global_load_lds(
                    (const __attribute__((address_space(1))) void*)ga,
                    (__attribute__((address_space(3))) void*)((__attribute__((address_space(3))) char*)Ash + c * 1024),
                    16, 0, 0);
            } else {
                const unsigned short* gb = B + (size_t)(n0 + (c - 8) * 16 + srow) * K + k0 + scol;
                __builtin_amdgcn_global_load_lds(
                    (const __attribute__((address_space(1))) void*)gb,
                    (__attribute__((address_space(3))) void*)((__attribute__((address_space(3))) char*)Bsh + (c - 8) * 1024),
                    16, 0, 0);
            }
        }
        __syncthreads();
        short8 af[4], bfr[WN];
#pragma unroll
        for (int i = 0; i < 4; ++i) {
            int ml = wave_m * 64 + i * 16 + l16;
            af[i] = ((const short8*)Ash)[ml * 4 + quad];
        }
#pragma unroll
        for (int j = 0; j < WN; ++j) {
            int nl = wave_n * (BN / 2) + j * 16 + l16;
            bfr[j] = ((const short8*)Bsh)[nl * 4 + quad];
        }
#pragma unroll
        for (int i = 0; i < 4; ++i)
#pragma unroll
            for (int j = 0; j < WN; ++j)
                acc[i][j] = __builtin_amdgcn_mfma_f32_16x16x32_bf16(af[i], bfr[j], acc[i][j], 0, 0, 0);
        __syncthreads();
    }
#pragma unroll
    for (int j = 0; j < WN; ++j) {
        int col = n0 + wave_n * (BN / 2) + j * 16 + l16;
        float bv = bias[col];
#pragma unroll
        for (int i = 0; i < 4; ++i) {
            int rowb = m0 + wave_m * 64 + i * 16 + quad * 4;
#pragma unroll
            for (int r = 0; r < 4; ++r)
                C[(size_t)(rowb + r) * Nn + col] = f2bf(tanhf(acc[i][j][r] + bv));
        }
    }
}

// ================= predict over item-sorted packed targets =================
__global__ __launch_bounds__(256) void predict_kernel(const unsigned short* __restrict__ dec_b,
                                                      const unsigned char* __restrict__ wdb8,
                                                      const float* __restrict__ b_dec,
                                                      const int4* __restrict__ st,
                                                      float* __restrict__ pred,
                                                      float* __restrict__ partials, int NT) {
    __shared__ float wsum[4];
    int wid = threadIdx.x >> 6, lane = threadIdx.x & 63;
    int base = (blockIdx.x * 4 + wid) * 4;
    float sq = 0.f;
    int4 tv[4];
    uint4 gv[4];
    uint2 wv[4];
#pragma unroll
    for (int t = 0; t < 4; ++t) tv[t] = st[min(base + t, NT - 1)];
#pragma unroll
    for (int t = 0; t < 4; ++t) {
        gv[t] = ((const uint4*)(dec_b + (size_t)tv[t].x * H0))[lane];
        wv[t] = ((const uint2*)(wdb8 + (size_t)tv[t].y * H0))[lane];
    }
#pragma unroll
    for (int t = 0; t < 4; ++t) {
        float wf[8];
        fp8x4_to_f32(wv[t].x, wf);
        fp8x4_to_f32(wv[t].y, wf + 4);
        float s = bflo(gv[t].x) * wf[0] + bfhi(gv[t].x) * wf[1]
                + bflo(gv[t].y) * wf[2] + bfhi(gv[t].y) * wf[3]
                + bflo(gv[t].z) * wf[4] + bfhi(gv[t].z) * wf[5]
                + bflo(gv[t].w) * wf[6] + bfhi(gv[t].w) * wf[7];
#pragma unroll
        for (int off = 32; off; off >>= 1) s += __shfl_xor(s, off, 64);
        if (lane == 0 && base + t < NT) {
            float p = s * FP8_INV + b_dec[tv[t].y];
            pred[tv[t].w] = p;
            float d = p - __int_as_float(tv[t].z);
            sq += d * d;
        }
    }
    if (lane == 0) wsum[wid] = sq;
    __syncthreads();
    if (threadIdx.x == 0) partials[blockIdx.x] = wsum[0] + wsum[1] + wsum[2] + wsum[3];
}

__global__ void loss_reduce(const float* __restrict__ partials, float* __restrict__ out_loss,
                            int nPart, float invNT) {
    __shared__ float s[256];
    int t = threadIdx.x;
    float a = 0.f;
    const float4* p4 = (const float4*)partials;
    int n4 = nPart >> 2;
    for (int i = t; i < n4; i += 256) {
        float4 v = p4[i];
        a += v.x + v.y + v.z + v.w;
    }
    for (int i = (n4 << 2) + t; i < nPart; i += 256) a += partials[i];
    s[t] = a;
    __syncthreads();
    for (int off = 128; off; off >>= 1) {
        if (t < off) s[t] += s[t + off];
        __syncthreads();
    }
    if (t == 0) out_loss[0] = s[0] * invNT;
}

extern "C" void kernel_launch(void* const* d_in, const int* in_sizes, int n_in,
                              void* d_out, int out_size, void* d_ws, size_t ws_size,
                              hipStream_t stream) {
    const int* user = (const int*)d_in[0];
    const int* item = (const int*)d_in[1];
    const float* rating = (const float*)d_in[2];
    const int* t_user = (const int*)d_in[3];
    const int* t_item = (const int*)d_in[4];
    const float* t_rating = (const float*)d_in[5];
    const float* W_enc = (const float*)d_in[6];
    const float* b_enc = (const float*)d_in[7];
    const float* W1 = (const float*)d_in[8];
    const float* b1 = (const float*)d_in[9];
    const float* W2 = (const float*)d_in[10];
    const float* b2 = (const float*)d_in[11];
    const float* W_dec = (const float*)d_in[12];
    const float* b_dec = (const float*)d_in[13];
    const int N = in_sizes[0];
    const int NT = in_sizes[3];

    char* ws = (char*)d_ws;
    size_t off = 0;
    auto alloc = [&](size_t bytes) {
        void* p = ws + off;
        off = (off + bytes + 255) & ~(size_t)255;
        return p;
    };
    unsigned char* wtb8 = (unsigned char*)alloc((size_t)NUM_ITEMS * H0);        // 25.6 MB
    unsigned char* wdb8 = (unsigned char*)alloc((size_t)NUM_ITEMS * H0);        // 25.6 MB
    unsigned short* xb = (unsigned short*)alloc((size_t)NUM_USERS * H0 * 2);    // 16 MB
    unsigned short* enc_b = (unsigned short*)alloc((size_t)NUM_USERS * LAT * 2);// 8 MB
    unsigned short* dec_b = (unsigned short*)alloc((size_t)NUM_USERS * H0 * 2); // 16 MB
    unsigned short* w1b = (unsigned short*)alloc((size_t)LAT * H0 * 2);
    unsigned short* w2b = (unsigned short*)alloc((size_t)H0 * LAT * 2);
    int* cntU = (int*)alloc((size_t)(NUM_USERS + ITEM_BINS) * 4);
    int* cntI = cntU + NUM_USERS;
    int* offsU = (int*)alloc((size_t)NUM_USERS * 4);
    int* curU = (int*)alloc((size_t)NUM_USERS * 4);
    int* offsI = (int*)alloc((size_t)ITEM_BINS * 4);
    int* curI = (int*)alloc((size_t)ITEM_BINS * 4);
    int2* s_pack = (int2*)alloc((size_t)N * 8);
    int4* st_pack = (int4*)alloc((size_t)NT * 16);
    const int predBlocks = (NT + 15) / 16;
    float* partials = (float*)alloc((size_t)predBlocks * 4);

    float* pred = (float*)d_out;
    float* loss = pred + NT;

    const int maxNNT = N > NT ? N : NT;
    const int SB = (maxNNT + 255) / 256;                 // 1024 scatter blocks
    const int TBX = (NUM_ITEMS + 63) / 64;               // 782
    const int TB = TBX * (H0 / 128);                     // 3128 transpose blocks
    const int DB = (NUM_ITEMS * H0) / 4096;              // 6250 W_dec cast blocks
    const int WB = 128;                                  // W1+W2 cast blocks

    hipMemsetAsync(cntU, 0, (size_t)(NUM_USERS + ITEM_BINS) * 4, stream);
    count_kernel<<<(maxNNT + 1023) / 1024, 256, 0, stream>>>(user, cntU, t_item, cntI, N, NT);
    scan_kernel<<<2, 1024, 0, stream>>>(cntU, offsU, curU, cntI, offsI, curI);
    mega_kernel<<<SB + TB + DB + WB, 256, 0, stream>>>(
        user, item, rating, curU, s_pack,
        t_user, t_item, t_rating, curI, st_pack,
        W_enc, wtb8, W_dec, wdb8, W1, w1b, W2, w2b,
        N, NT, SB, TB, DB);
    agg_kernel<<<NUM_USERS, 256, 0, stream>>>(wtb8, offsU, curU, s_pack, b_enc, xb);
    gemm_mfma<64><<<dim3(NUM_USERS / 128, LAT / 64), 256, 0, stream>>>(xb, w1b, b1, enc_b, LAT, H0);
    gemm_mfma<64><<<dim3(NUM_USERS / 128, H0 / 64), 256, 0, stream>>>(enc_b, w2b, b2, dec_b, H0, LAT);
    predict_kernel<<<predBlocks, 256, 0, stream>>>(dec_b, wdb8, b_dec, st_pack, pred, partials, NT);
    loss_reduce<<<1, 256, 0, stream>>>(partials, loss, predBlocks, 1.0f / NT);
}